// Round 4
// baseline (1475.306 us; speedup 1.0000x reference)
//
#include <hip/hip_runtime.h>
#include <hip/hip_bf16.h>
#include <stdint.h>

typedef __attribute__((ext_vector_type(8))) short bf16x8;
typedef __attribute__((ext_vector_type(4))) float f32x4;
typedef __attribute__((ext_vector_type(2))) float f32x2;
typedef __attribute__((ext_vector_type(4))) short short4v;

#define UNITS 1024
#define BATCH 32
#define SEQ 4096
#define CHUNK 64
#define NCHUNK (SEQ / CHUNK)   // 64
#define PAD 8
#define LDK (UNITS + PAD)      // shorts per LDS row
#define BK 128                 // k-tile (elements)
#define NKT (UNITS / BK)       // 8 k-tiles per task
#define TASKS 8                // tasks (chunks) per persistent block

static __device__ __forceinline__ float bf2f(unsigned short u) {
    union { unsigned int i; float f; } x; x.i = ((unsigned int)u) << 16; return x.f;
}
static __device__ __forceinline__ unsigned short f2bf(float f) {
    __hip_bfloat16 h = __float2bfloat16(f);   // RNE
    return *reinterpret_cast<unsigned short*>(&h);
}
static __device__ __forceinline__ float fast_tanh(float x) {
    float e = __expf(2.0f * x);               // saturates correctly at +/-inf
    return 1.0f - 2.0f / (e + 1.0f);
}

// K0: U_wT[v][u] = bf16(U_w[u][v]); 32x32 LDS tile transpose
__global__ void k_transpose_cast(const float* __restrict__ Uw,
                                 unsigned short* __restrict__ UwT) {
    __shared__ float tile[32][33];
    const int ti = blockIdx.x, tj = blockIdx.y;
    const int c = threadIdx.x;   // 0..31
    const int r0 = threadIdx.y;  // 0..7
#pragma unroll
    for (int rr = 0; rr < 4; ++rr) {
        int r = r0 + rr * 8;
        tile[r][c] = Uw[(size_t)(ti * 32 + r) * UNITS + tj * 32 + c];
    }
    __syncthreads();
#pragma unroll
    for (int rr = 0; rr < 4; ++rr) {
        int rv = r0 + rr * 8;
        UwT[(size_t)(tj * 32 + rv) * UNITS + ti * 32 + c] = f2bf(tile[c][rv]);
    }
}

// K1a: ws partials. Block ks (32 blocks) owns k-rows [ks*32, ks*32+32).
// Ww rows are read ONCE total (held in registers), looped over all 32 batches.
__global__ void k_ws_part(const float* __restrict__ s_prev, const float* __restrict__ Ww,
                          float* __restrict__ part) {
    const int ks = blockIdx.x;          // 0..31
    const int col0 = threadIdx.x * 4;   // 0..1020
    f32x4 wreg[32];
#pragma unroll
    for (int u = 0; u < 32; ++u)
        wreg[u] = *reinterpret_cast<const f32x4*>(&Ww[(size_t)(ks * 32 + u) * UNITS + col0]);
    for (int b = 0; b < BATCH; ++b) {
        f32x4 acc = (f32x4)(0.f);
#pragma unroll
        for (int u = 0; u < 32; ++u) {
            const float s = s_prev[(size_t)b * UNITS + ks * 32 + u];
            acc.x = fmaf(s, wreg[u].x, acc.x);
            acc.y = fmaf(s, wreg[u].y, acc.y);
            acc.z = fmaf(s, wreg[u].z, acc.z);
            acc.w = fmaf(s, wreg[u].w, acc.w);
        }
        *reinterpret_cast<f32x4*>(&part[((size_t)b * 32 + ks) * UNITS + col0]) = acc;
    }
}

// K1b: ws_vec[b][v] = sum_ks part + W_b + U_b
__global__ void k_ws_red(const float* __restrict__ part, const float* __restrict__ Wb,
                         const float* __restrict__ Ub, float* __restrict__ ws_vec) {
    const int b = blockIdx.x;
    const int col0 = threadIdx.x * 4;
    f32x4 acc = *reinterpret_cast<const f32x4*>(&Wb[col0]);
    f32x4 ub  = *reinterpret_cast<const f32x4*>(&Ub[col0]);
    acc.x += ub.x; acc.y += ub.y; acc.z += ub.z; acc.w += ub.w;
#pragma unroll
    for (int ks = 0; ks < 32; ++ks) {
        f32x4 p = *reinterpret_cast<const f32x4*>(&part[((size_t)b * 32 + ks) * UNITS + col0]);
        acc.x += p.x; acc.y += p.y; acc.z += p.z; acc.w += p.w;
    }
    *reinterpret_cast<f32x4*>(&ws_vec[(size_t)b * UNITS + col0]) = acc;
}

// K2: persistent fused kernel. 256 blocks x 8 tasks. Depth-2 register pipeline:
// while MFMA consumes LDS k-tile kt, fp32 tile kt+1 sits in regs and kt+2 loads.
__launch_bounds__(512, 2)
__global__ void k_score_ctx(const float* __restrict__ hidden,
                            const unsigned short* __restrict__ UwT,
                            const float* __restrict__ ws_vec,
                            const float* __restrict__ Vw,
                            const float* __restrict__ Vb,
                            float* __restrict__ scores,
                            float* __restrict__ mstat,
                            float* __restrict__ lstat,
                            float* __restrict__ ctx_part) {
    __shared__ unsigned short h_lds[CHUNK * LDK];  // 129 KB bf16 row chunk
    __shared__ float ws_lds[UNITS];
    __shared__ float v_lds[UNITS];
    __shared__ float scpart[8][CHUNK];
    __shared__ float esc[CHUNK];

    const int tid = threadIdx.x;
    const int blk = blockIdx.x;
    const int b      = blk >> 3;           // 8 blocks per batch
    const int chunk0 = (blk & 7) * TASKS;  // this block's first chunk
    const int lane = tid & 63;
    const int w    = tid >> 6;             // wave 0..7
    const int l15  = lane & 15;
    const int l4   = lane >> 4;
    const int srow = tid >> 5;             // 0..15 (stage row base)
    const int sc0  = (tid & 31) * 4;       // stage k-offset within tile

    for (int i = tid; i < UNITS; i += 512) {
        ws_lds[i] = ws_vec[(size_t)b * UNITS + i];
        v_lds[i]  = Vw[i];
    }
    const float vb0 = Vb[0];

    auto issue = [&](const float* hb, int kt, f32x4* P) {
#pragma unroll
        for (int j = 0; j < 4; ++j)
            P[j] = *reinterpret_cast<const f32x4*>(
                hb + (size_t)(srow + j * 16) * UNITS + kt * BK + sc0);
    };
    auto swrite = [&](int kt, f32x4* P) {
#pragma unroll
        for (int j = 0; j < 4; ++j) {
            short4v s;
            s.x = (short)f2bf(P[j].x); s.y = (short)f2bf(P[j].y);
            s.z = (short)f2bf(P[j].z); s.w = (short)f2bf(P[j].w);
            *reinterpret_cast<short4v*>(&h_lds[(srow + j * 16) * LDK + kt * BK + sc0]) = s;
        }
    };
    auto gemm_tile = [&](int kt, f32x4 (&acc)[4][4], int colbase) {
#pragma unroll
        for (int ks = 0; ks < 4; ++ks) {
            const int k0 = kt * BK + ks * 32;
            bf16x8 af[4], bfr[4];
#pragma unroll
            for (int fr = 0; fr < 4; ++fr)
                af[fr] = *reinterpret_cast<const bf16x8*>(
                    &h_lds[(fr * 16 + l15) * LDK + k0 + l4 * 8]);
#pragma unroll
            for (int fc = 0; fc < 4; ++fc)
                bfr[fc] = *reinterpret_cast<const bf16x8*>(
                    &UwT[(size_t)(colbase + fc * 16 + l15) * UNITS + k0 + l4 * 8]);
#pragma unroll
            for (int fr = 0; fr < 4; ++fr)
#pragma unroll
                for (int fc = 0; fc < 4; ++fc)
                    acc[fr][fc] = __builtin_amdgcn_mfma_f32_16x16x32_bf16(
                        af[fr], bfr[fc], acc[fr][fc], 0, 0, 0);
        }
    };
    auto epi = [&](f32x4 (&acc)[4][4], int colbase, float (&spart)[4][4]) {
#pragma unroll
        for (int fc = 0; fc < 4; ++fc) {
            const int col = colbase + fc * 16 + l15;
            const float wsv = ws_lds[col];
            const float vv  = v_lds[col];
#pragma unroll
            for (int fr = 0; fr < 4; ++fr)
#pragma unroll
                for (int j = 0; j < 4; ++j)
                    spart[fr][j] = fmaf(fast_tanh(wsv + acc[fr][fc][j]), vv, spart[fr][j]);
        }
    };

    f32x4 PA[4], PB[4];
    {
        const float* hb0 = hidden + ((size_t)b * SEQ + (size_t)chunk0 * CHUNK) * UNITS;
        issue(hb0, 0, PA);
        issue(hb0, 1, PB);
    }

    for (int t = 0; t < TASKS; ++t) {
        const int chunk = chunk0 + t;
        const float* hb  = hidden + ((size_t)b * SEQ + (size_t)chunk * CHUNK) * UNITS;
        const int tn = (t < TASKS - 1) ? t + 1 : t;   // clamp: last task re-reads self (unused)
        const float* hbn = hidden + ((size_t)b * SEQ + (size_t)(chunk0 + tn) * CHUNK) * UNITS;

        float spart[4][4];
#pragma unroll
        for (int fr = 0; fr < 4; ++fr)
#pragma unroll
            for (int j = 0; j < 4; ++j) spart[fr][j] = 0.f;

        f32x4 acc[4][4];
#pragma unroll
        for (int fr = 0; fr < 4; ++fr)
#pragma unroll
            for (int fc = 0; fc < 4; ++fc) acc[fr][fc] = (f32x4)(0.f);

        // ---- phase A: pipelined stage + GEMM over cols 0..511 ----
#pragma unroll
        for (int kp = 0; kp < 4; ++kp) {
            const int kt0 = kp * 2, kt1 = kp * 2 + 1;
            swrite(kt0, PA);
            if (kt0 + 2 < NKT) issue(hb, kt0 + 2, PA);
            else               issue(hbn, kt0 + 2 - NKT, PA);
            __syncthreads();
            gemm_tile(kt0, acc, w * 64);
            swrite(kt1, PB);
            if (kt1 + 2 < NKT) issue(hb, kt1 + 2, PB);
            else               issue(hbn, kt1 + 2 - NKT, PB);
            __syncthreads();
            gemm_tile(kt1, acc, w * 64);
        }
        epi(acc, w * 64, spart);

        // ---- phase B: cols 512..1023, LDS fully staged, no barriers ----
#pragma unroll
        for (int fr = 0; fr < 4; ++fr)
#pragma unroll
            for (int fc = 0; fc < 4; ++fc) acc[fr][fc] = (f32x4)(0.f);
#pragma unroll 2
        for (int kt = 0; kt < NKT; ++kt)
            gemm_tile(kt, acc, 512 + w * 64);
        epi(acc, 512 + w * 64, spart);

        // ---- reduce cols across 16-lane groups ----
#pragma unroll
        for (int fr = 0; fr < 4; ++fr)
#pragma unroll
            for (int j = 0; j < 4; ++j) {
                float v = spart[fr][j];
                v += __shfl_xor(v, 1);
                v += __shfl_xor(v, 2);
                v += __shfl_xor(v, 4);
                v += __shfl_xor(v, 8);
                spart[fr][j] = v;
            }
        if (l15 == 0) {
#pragma unroll
            for (int fr = 0; fr < 4; ++fr)
#pragma unroll
                for (int j = 0; j < 4; ++j)
                    scpart[w][fr * 16 + l4 * 4 + j] = spart[fr][j];
        }
        __syncthreads();

        if (tid < CHUNK) {   // wave 0: scores + chunk softmax stats
            float sc = vb0;
#pragma unroll
            for (int ww = 0; ww < 8; ++ww) sc += scpart[ww][tid];
            scores[(size_t)b * SEQ + chunk * CHUNK + tid] = sc;
            float m = sc;
#pragma unroll
            for (int mk = 1; mk < 64; mk <<= 1) m = fmaxf(m, __shfl_xor(m, mk));
            float e = __expf(sc - m);
            esc[tid] = e;
            float l = e;
#pragma unroll
            for (int mk = 1; mk < 64; mk <<= 1) l += __shfl_xor(l, mk);
            if (tid == 0) {
                mstat[b * NCHUNK + chunk] = m;
                lstat[b * NCHUNK + chunk] = l;
            }
        }
        __syncthreads();

        // ---- partial context from LDS bf16 copy ----
        {
            const int u0 = tid * 2;
            float a0 = 0.f, a1 = 0.f;
#pragma unroll 8
            for (int s = 0; s < CHUNK; ++s) {
                unsigned int p = *reinterpret_cast<const unsigned int*>(&h_lds[s * LDK + u0]);
                float e = esc[s];
                a0 = fmaf(e, bf2f((unsigned short)(p & 0xffffu)), a0);
                a1 = fmaf(e, bf2f((unsigned short)(p >> 16)), a1);
            }
            f32x2 o; o.x = a0; o.y = a1;
            *reinterpret_cast<f32x2*>(
                &ctx_part[((size_t)(b * NCHUNK + chunk)) * UNITS + u0]) = o;
        }
        __syncthreads();   // protect h_lds/esc before next task overwrites
    }
}

// K3: global softmax over S per batch -> weights output
__global__ void k_weights(const float* __restrict__ scores, float* __restrict__ out_w) {
    const int b = blockIdx.x;
    const int tid = threadIdx.x;
    __shared__ float red[8];
    float sc[16];
#pragma unroll
    for (int i = 0; i < 16; ++i) sc[i] = scores[(size_t)b * SEQ + tid + i * 256];
    float m = sc[0];
#pragma unroll
    for (int i = 1; i < 16; ++i) m = fmaxf(m, sc[i]);
#pragma unroll
    for (int mk = 1; mk < 64; mk <<= 1) m = fmaxf(m, __shfl_xor(m, mk));
    if ((tid & 63) == 0) red[tid >> 6] = m;
    __syncthreads();
    m = fmaxf(fmaxf(red[0], red[1]), fmaxf(red[2], red[3]));
    __syncthreads();
    float l = 0.f;
#pragma unroll
    for (int i = 0; i < 16; ++i) { sc[i] = __expf(sc[i] - m); l += sc[i]; }
#pragma unroll
    for (int mk = 1; mk < 64; mk <<= 1) l += __shfl_xor(l, mk);
    if ((tid & 63) == 0) red[tid >> 6] = l;
    __syncthreads();
    l = red[0] + red[1] + red[2] + red[3];
    const float inv = 1.0f / l;
#pragma unroll
    for (int i = 0; i < 16; ++i)
        out_w[(size_t)b * SEQ + tid + i * 256] = sc[i] * inv;
}

// K4: combine chunk partials -> context output
__global__ void k_ctx_reduce(const float* __restrict__ mstat, const float* __restrict__ lstat,
                             const float* __restrict__ ctx_part, float* __restrict__ out_ctx) {
    const int b = blockIdx.x;
    const int tid = threadIdx.x;
    __shared__ float m_l[NCHUNK], l_l[NCHUNK], f_l[NCHUNK];
    if (tid < NCHUNK) { m_l[tid] = mstat[b * NCHUNK + tid]; l_l[tid] = lstat[b * NCHUNK + tid]; }
    __syncthreads();
    float M = -1e30f;
#pragma unroll 8
    for (int c = 0; c < NCHUNK; ++c) M = fmaxf(M, m_l[c]);
    __syncthreads();
    if (tid < NCHUNK) f_l[tid] = __expf(m_l[tid] - M);
    __syncthreads();
    float L = 0.f;
#pragma unroll 8
    for (int c = 0; c < NCHUNK; ++c) L += f_l[c] * l_l[c];
    const float inv = 1.0f / L;
    const int u = tid * 4;
    f32x4 acc = (f32x4)(0.f);
#pragma unroll 4
    for (int c = 0; c < NCHUNK; ++c) {
        float f = f_l[c];
        f32x4 v = *reinterpret_cast<const f32x4*>(
            &ctx_part[((size_t)(b * NCHUNK + c)) * UNITS + u]);
        acc.x = fmaf(f, v.x, acc.x);
        acc.y = fmaf(f, v.y, acc.y);
        acc.z = fmaf(f, v.z, acc.z);
        acc.w = fmaf(f, v.w, acc.w);
    }
    acc.x *= inv; acc.y *= inv; acc.z *= inv; acc.w *= inv;
    *reinterpret_cast<f32x4*>(&out_ctx[(size_t)b * UNITS + u]) = acc;
}

extern "C" void kernel_launch(void* const* d_in, const int* in_sizes, int n_in,
                              void* d_out, int out_size, void* d_ws, size_t ws_size,
                              hipStream_t stream) {
    const float* s_prev = (const float*)d_in[0];
    const float* hidden = (const float*)d_in[1];
    const float* Ww     = (const float*)d_in[2];
    const float* Wb     = (const float*)d_in[3];
    const float* Uw     = (const float*)d_in[4];
    const float* Ub     = (const float*)d_in[5];
    const float* Vw     = (const float*)d_in[6];
    const float* Vb     = (const float*)d_in[7];

    float* out_ctx = (float*)d_out;                 // [32,1024]
    float* out_w   = (float*)d_out + BATCH * UNITS; // [32,4096]

    char* wsb = (char*)d_ws;
    unsigned short* UwT = (unsigned short*)wsb;                       // 2 MiB bf16
    float* ws_vec = (float*)(wsb + (2u << 20));                       // 128 KiB
    float* scores = (float*)(wsb + (2u << 20) + 131072);              // 512 KiB
    float* mstat  = (float*)(wsb + (2u << 20) + 131072 + 524288);     // 8 KiB
    float* lstat  = mstat + BATCH * NCHUNK;                           // 8 KiB
    float* ctx_part = lstat + BATCH * NCHUNK;                         // 8 MiB
    float* ws_part  = ctx_part;   // 4 MiB alias; lifetime ends before ctx_part written

    hipLaunchKernelGGL(k_transpose_cast, dim3(32, 32), dim3(32, 8), 0, stream, Uw, UwT);
    hipLaunchKernelGGL(k_ws_part, dim3(32), dim3(256), 0, stream, s_prev, Ww, ws_part);
    hipLaunchKernelGGL(k_ws_red, dim3(BATCH), dim3(256), 0, stream, ws_part, Wb, Ub, ws_vec);
    hipLaunchKernelGGL(k_score_ctx, dim3(256), dim3(512), 0, stream,
                       hidden, UwT, ws_vec, Vw, Vb, scores, mstat, lstat, ctx_part);
    hipLaunchKernelGGL(k_weights, dim3(BATCH), dim3(256), 0, stream, scores, out_w);
    hipLaunchKernelGGL(k_ctx_reduce, dim3(BATCH), dim3(256), 0, stream,
                       mstat, lstat, ctx_part, out_ctx);
}